// Round 12
// baseline (463.906 us; speedup 1.0000x reference)
//
#include <hip/hip_runtime.h>
#include <hip/hip_fp16.h>
#include <math.h>

#define FEAT 128
#define HID  64
#define BSH  7                 // 128 dst-nodes per bucket
#define BNODES (1 << BSH)
#define PB   256               // partition blocks (256: full-chip parallelism)
#define SRCM ((1u << 25) - 1)  // src in low 25 bits, dst_local in high 7
#define PSPLIT 16              // pool splits per group

typedef _Float16 f16_t;
typedef f16_t half8 __attribute__((ext_vector_type(8)));
typedef float  f32x4 __attribute__((ext_vector_type(4)));

// ---------------- stage 1: edge partition by dst-bucket ----------------
// block 0 additionally zeroes pooled[] and the pool ticket counter (replaces
// two hipMemsetAsync dispatches; stream order guarantees visibility).

__global__ void part_hist_k(const int* __restrict__ dst, int* __restrict__ table,
                            float* __restrict__ pooled, int* __restrict__ ticket,
                            int e, int nb, int gh) {
    if (blockIdx.x == 0) {
        for (int i = threadIdx.x; i < gh; i += 256) pooled[i] = 0.0f;
        if (threadIdx.x == 0) ticket[0] = 0;
    }
    __shared__ int lcnt[1024];
    for (int i = threadIdx.x; i < nb; i += 256) lcnt[i] = 0;
    __syncthreads();
    int eb = (e + PB - 1) / PB;
    int lo = blockIdx.x * eb, hi = min(lo + eb, e);
    for (int i = lo + threadIdx.x; i < hi; i += 256)
        atomicAdd(&lcnt[dst[i] >> BSH], 1);
    __syncthreads();
    for (int k = threadIdx.x; k < nb; k += 256)
        table[k * PB + blockIdx.x] = lcnt[k];
}

__global__ void scan1_k(int* __restrict__ data, int* __restrict__ aux, int L) {
    __shared__ int s[1024];
    int gid = blockIdx.x * 1024 + threadIdx.x;
    int v = (gid < L) ? data[gid] : 0;
    s[threadIdx.x] = v;
    __syncthreads();
    for (int off = 1; off < 1024; off <<= 1) {
        int t = (threadIdx.x >= off) ? s[threadIdx.x - off] : 0;
        __syncthreads();
        s[threadIdx.x] += t;
        __syncthreads();
    }
    if (gid < L) data[gid] = s[threadIdx.x] - v;            // exclusive in block
    if (threadIdx.x == 1023) aux[blockIdx.x] = s[1023];     // block total
}

__global__ void scan2_k(int* aux, int naux) {
    __shared__ int s[1024];
    int v = (threadIdx.x < naux) ? aux[threadIdx.x] : 0;
    s[threadIdx.x] = v;
    __syncthreads();
    for (int off = 1; off < 1024; off <<= 1) {
        int t = (threadIdx.x >= off) ? s[threadIdx.x - off] : 0;
        __syncthreads();
        s[threadIdx.x] += t;
        __syncthreads();
    }
    if (threadIdx.x < naux) aux[threadIdx.x] = s[threadIdx.x] - v;
}

__global__ void part_scatter_k(const int* __restrict__ src, const int* __restrict__ dst,
                               const int* __restrict__ table, const int* __restrict__ aux,
                               unsigned* __restrict__ packed, int e, int nb) {
    __shared__ int loff[1024];
    for (int k = threadIdx.x; k < nb; k += 256) {
        int idx = k * PB + blockIdx.x;
        loff[k] = table[idx] + aux[idx >> 10];
    }
    __syncthreads();
    int eb = (e + PB - 1) / PB;
    int lo = blockIdx.x * eb, hi = min(lo + eb, e);
    for (int i = lo + threadIdx.x; i < hi; i += 256) {
        int d = dst[i];
        int p = atomicAdd(&loff[d >> BSH], 1);
        packed[p] = ((unsigned)(d & (BNODES - 1)) << 25) | (unsigned)src[i];
    }
}

// ---------------- stage 2: per-bucket counting sort -> per-node CSR + dinv ----

__global__ void bucket_sort_k(const unsigned* __restrict__ packed,
                              const int* __restrict__ table, const int* __restrict__ aux,
                              int* __restrict__ col, int* __restrict__ rowptr,
                              float* __restrict__ dinv, int n, int e, int nb) {
    __shared__ int cnt[BNODES];
    __shared__ int s[BNODES];
    __shared__ int cur[BNODES];
    const int k = blockIdx.x;
    const int t = threadIdx.x;
    if (t < BNODES) cnt[t] = 0;
    __syncthreads();
    int i0 = k * PB;
    int i1 = (k + 1) * PB;
    const int bs = table[i0] + aux[i0 >> 10];
    const int be = (k + 1 < nb) ? (table[i1] + aux[i1 >> 10]) : e;
    for (int i = bs + t; i < be; i += 256)
        atomicAdd(&cnt[packed[i] >> 25], 1);
    __syncthreads();
    if (t < BNODES) s[t] = cnt[t];
    __syncthreads();
    for (int off = 1; off < BNODES; off <<= 1) {
        int v = (t < BNODES && t >= off) ? s[t - off] : 0;
        __syncthreads();
        if (t < BNODES) s[t] += v;
        __syncthreads();
    }
    if (t < BNODES) {
        int base = bs + s[t] - cnt[t];
        cur[t] = base;
        int node = (k << BSH) + t;
        if (node < n) {
            rowptr[node] = base;
            dinv[node] = 1.0f / sqrtf(1.0f + (float)cnt[t]);
            if (node == n - 1) rowptr[n] = base + cnt[t];
        }
    }
    __syncthreads();
    for (int i = bs + t; i < be; i += 256) {
        unsigned u = packed[i];
        int p = atomicAdd(&cur[u >> 25], 1);
        col[p] = (int)(u & SRCM);
    }
}

// ---------------- dense transform: out[n,64] = fp16((X[n,128] @ W1) * dinv[row]) ----

__global__ __launch_bounds__(256, 3)
void gemm_tile_k(const float* __restrict__ X, const float* __restrict__ W,
                 const float* __restrict__ dinv, __half* __restrict__ out, int n) {
    constexpr int K = FEAT;
    __shared__ float sX[64][K + 4];
    __shared__ float sW[64][64];       // one 64-row slab of W
    const int row0 = blockIdx.x * 64;
    const int t  = threadIdx.x;
    const int tx = t & 15;
    const int ty = t >> 4;

    const float* xb = X + (size_t)row0 * K;
#pragma unroll
    for (int it = 0; it < K / 16; ++it) {
        int fl = it * 1024 + t * 4;
        int r  = fl >> 7;
        int k  = fl & (K - 1);
        float4 v = make_float4(0.f, 0.f, 0.f, 0.f);
        if (row0 + r < n) v = *(const float4*)(xb + fl);
        *(float4*)&sX[r][k] = v;
    }

    float acc[4][4] = {};
#pragma unroll
    for (int ph = 0; ph < K / 64; ++ph) {
        __syncthreads();
#pragma unroll
        for (int it = 0; it < 4; ++it) {
            int fl = it * 1024 + t * 4;
            *(float4*)&sW[fl >> 6][fl & 63] = *(const float4*)(W + ph * 64 * HID + fl);
        }
        __syncthreads();

#pragma unroll 8
        for (int k = 0; k < 64; k += 4) {
            float4 a[4], b[4];
#pragma unroll
            for (int i = 0; i < 4; i++) a[i] = *(float4*)&sX[ty * 4 + i][ph * 64 + k];
#pragma unroll
            for (int j = 0; j < 4; j++) b[j] = *(float4*)&sW[k + j][tx * 4];
#pragma unroll
            for (int i = 0; i < 4; i++) {
                acc[i][0] = fmaf(a[i].x, b[0].x, acc[i][0]);
                acc[i][1] = fmaf(a[i].x, b[0].y, acc[i][1]);
                acc[i][2] = fmaf(a[i].x, b[0].z, acc[i][2]);
                acc[i][3] = fmaf(a[i].x, b[0].w, acc[i][3]);
                acc[i][0] = fmaf(a[i].y, b[1].x, acc[i][0]);
                acc[i][1] = fmaf(a[i].y, b[1].y, acc[i][1]);
                acc[i][2] = fmaf(a[i].y, b[1].z, acc[i][2]);
                acc[i][3] = fmaf(a[i].y, b[1].w, acc[i][3]);
                acc[i][0] = fmaf(a[i].z, b[2].x, acc[i][0]);
                acc[i][1] = fmaf(a[i].z, b[2].y, acc[i][1]);
                acc[i][2] = fmaf(a[i].z, b[2].z, acc[i][2]);
                acc[i][3] = fmaf(a[i].z, b[2].w, acc[i][3]);
                acc[i][0] = fmaf(a[i].w, b[3].x, acc[i][0]);
                acc[i][1] = fmaf(a[i].w, b[3].y, acc[i][1]);
                acc[i][2] = fmaf(a[i].w, b[3].z, acc[i][2]);
                acc[i][3] = fmaf(a[i].w, b[3].w, acc[i][3]);
            }
        }
    }

#pragma unroll
    for (int i = 0; i < 4; i++) {
        int gr = row0 + ty * 4 + i;
        if (gr < n) {
            float sc = dinv[gr];
            union { __half2 h[2]; unsigned long long u; } pk;
            pk.h[0] = __floats2half2_rn(acc[i][0] * sc, acc[i][1] * sc);
            pk.h[1] = __floats2half2_rn(acc[i][2] * sc, acc[i][3] * sc);
            *(unsigned long long*)(out + (size_t)gr * HID + tx * 4) = pk.u;
        }
    }
}

// ---------------- layer-1 gather + MFMA t2 fused (512 thr = 16 nodes = 1 strip) ----
// Gather phase identical to the proven gather1 (32 lanes/node). h staged in LDS
// (stride 72 halves: kills the 16-way bank conflict on fragment reads), then
// waves 0..3 each compute one 16-col tile of (h @ W2)*dinv via 2 MFMAs.
// NOTE: out must NOT alias the gather input tS (random reads across all nodes
// race with the strip writes — that was round 11's 7e-3 corruption).

__global__ __launch_bounds__(512)
void gather1t2_k(const __half* __restrict__ tS, const int* __restrict__ rowptr,
                 const int* __restrict__ col, const float* __restrict__ dinv,
                 const float* __restrict__ b, const float* __restrict__ W2,
                 __half* __restrict__ out, int n) {
    __shared__ __half sh[16][72];      // h rows (stride 72: 2-way banks, 16B-aligned frags)
    const int tid  = threadIdx.x;
    const int nl   = tid >> 5;         // node-local 0..15
    const int lane = tid & 31;
    const int r0   = blockIdx.x * 16;
    const int node = r0 + nl;

    float h0 = 0.f, h1 = 0.f;
    if (node < n) {
        int beg = rowptr[node], end = rowptr[node + 1];
        const __half2* tl = (const __half2*)tS + lane;   // row stride = 32 half2
        float2 acc = __half22float2(tl[node * 32]);      // self-loop term
        int e = beg;
        for (; e + 16 <= end; e += 16) {
            int s[16];
            __half2 v[16];
#pragma unroll
            for (int j = 0; j < 16; j++) s[j] = col[e + j];
#pragma unroll
            for (int j = 0; j < 16; j++) v[j] = tl[s[j] * 32];
            float2 t0 = make_float2(0.f, 0.f), t1 = make_float2(0.f, 0.f);
#pragma unroll
            for (int j = 0; j < 8; j++) {
                float2 f = __half22float2(v[j]);
                t0.x += f.x; t0.y += f.y;
            }
#pragma unroll
            for (int j = 8; j < 16; j++) {
                float2 f = __half22float2(v[j]);
                t1.x += f.x; t1.y += f.y;
            }
            acc.x += t0.x + t1.x;
            acc.y += t0.y + t1.y;
        }
        for (; e + 4 <= end; e += 4) {
            __half2 v0 = tl[col[e] * 32];
            __half2 v1 = tl[col[e + 1] * 32];
            __half2 v2 = tl[col[e + 2] * 32];
            __half2 v3 = tl[col[e + 3] * 32];
            float2 f0 = __half22float2(v0), f1 = __half22float2(v1);
            float2 f2 = __half22float2(v2), f3 = __half22float2(v3);
            acc.x += (f0.x + f1.x) + (f2.x + f3.x);
            acc.y += (f0.y + f1.y) + (f2.y + f3.y);
        }
        for (; e < end; ++e) {
            float2 f = __half22float2(tl[col[e] * 32]);
            acc.x += f.x; acc.y += f.y;
        }
        float d = dinv[node];
        float2 bb = *(const float2*)(b + 2 * lane);
        h0 = fmaxf(fmaf(d, acc.x, bb.x), 0.0f);
        h1 = fmaxf(fmaf(d, acc.y, bb.y), 0.0f);
    }
    *(__half2*)&sh[nl][2 * lane] = __floats2half2_rn(h0, h1);
    __syncthreads();

    const int w = tid >> 6;            // wave 0..7
    if (w < 4) {
        const int l    = tid & 63;
        const int colc = l & 15;
        const int kb   = l >> 4;       // 0..3
        const int t    = w;            // 16-col tile
        // B-frags (W2 fp32 -> fp16; L2-resident, 16 scalar loads/lane)
        half8 b0, b1;
#pragma unroll
        for (int j = 0; j < 8; ++j)
            b0[j] = (f16_t)W2[(kb * 8 + j) * HID + t * 16 + colc];
#pragma unroll
        for (int j = 0; j < 8; ++j)
            b1[j] = (f16_t)W2[(32 + kb * 8 + j) * HID + t * 16 + colc];
        // A-frags from LDS: row = colc, k = kb*8 (+32)
        half8 a0 = *(const half8*)&sh[colc][kb * 8];
        half8 a1 = *(const half8*)&sh[colc][32 + kb * 8];
        f32x4 acc = {};
        acc = __builtin_amdgcn_mfma_f32_16x16x32_f16(a0, b0, acc, 0, 0, 0);
        acc = __builtin_amdgcn_mfma_f32_16x16x32_f16(a1, b1, acc, 0, 0, 0);
        const int rbase = r0 + kb * 4;
#pragma unroll
        for (int r = 0; r < 4; ++r) {
            int gr = rbase + r;
            if (gr < n) {
                float dv = dinv[gr];
                out[(size_t)gr * HID + t * 16 + colc] = __float2half(acc[r] * dv);
            }
        }
    }
}

// ---------------- layer-2 gather (logits fused; h written fp16 for pool) ----

__global__ void gather2_k(const __half* __restrict__ tS, const int* __restrict__ rowptr,
                          const int* __restrict__ col, const float* __restrict__ dinv,
                          const float* __restrict__ b, __half* __restrict__ out,
                          const float* __restrict__ Wa, const float* __restrict__ ba,
                          float* __restrict__ logits, int n) {
    int node = (int)((blockIdx.x * (size_t)blockDim.x + threadIdx.x) >> 5);
    int lane = threadIdx.x & 31;
    if (node >= n) return;
    int beg = rowptr[node], end = rowptr[node + 1];
    const __half2* tl = (const __half2*)tS + lane;
    float2 acc = __half22float2(tl[node * 32]);
    int e = beg;
    for (; e + 16 <= end; e += 16) {
        int s[16];
        __half2 v[16];
#pragma unroll
        for (int j = 0; j < 16; j++) s[j] = col[e + j];
#pragma unroll
        for (int j = 0; j < 16; j++) v[j] = tl[s[j] * 32];
        float2 t0 = make_float2(0.f, 0.f), t1 = make_float2(0.f, 0.f);
#pragma unroll
        for (int j = 0; j < 8; j++) {
            float2 f = __half22float2(v[j]);
            t0.x += f.x; t0.y += f.y;
        }
#pragma unroll
        for (int j = 8; j < 16; j++) {
            float2 f = __half22float2(v[j]);
            t1.x += f.x; t1.y += f.y;
        }
        acc.x += t0.x + t1.x;
        acc.y += t0.y + t1.y;
    }
    for (; e + 4 <= end; e += 4) {
        __half2 v0 = tl[col[e] * 32];
        __half2 v1 = tl[col[e + 1] * 32];
        __half2 v2 = tl[col[e + 2] * 32];
        __half2 v3 = tl[col[e + 3] * 32];
        float2 f0 = __half22float2(v0), f1 = __half22float2(v1);
        float2 f2 = __half22float2(v2), f3 = __half22float2(v3);
        acc.x += (f0.x + f1.x) + (f2.x + f3.x);
        acc.y += (f0.y + f1.y) + (f2.y + f3.y);
    }
    for (; e < end; ++e) {
        float2 f = __half22float2(tl[col[e] * 32]);
        acc.x += f.x; acc.y += f.y;
    }
    float d = dinv[node];
    float2 bb = *(const float2*)(b + 2 * lane);
    float h0 = fmaxf(fmaf(d, acc.x, bb.x), 0.0f);
    float h1 = fmaxf(fmaf(d, acc.y, bb.y), 0.0f);
    ((__half2*)out)[node * 32 + lane] = __floats2half2_rn(h0, h1);
    float2 wa = *(const float2*)(Wa + 2 * lane);
    float p = h0 * wa.x + h1 * wa.y;
#pragma unroll
    for (int off = 16; off > 0; off >>= 1) p += __shfl_down(p, off, 32);
    if (lane == 0) logits[node] = p + ba[0];
}

// ---------------- fused mean-pool + value head (ticket: last block finishes) ----

__global__ void poolvalue_k(const __half* __restrict__ h, const int* __restrict__ batch,
                            float* __restrict__ pooled, int* __restrict__ ticket,
                            const float* __restrict__ Wc, const float* __restrict__ bc,
                            float* __restrict__ val, int n, int g) {
    const int gid  = blockIdx.x / PSPLIT;
    const int part = blockIdx.x % PSPLIT;
    int lo = 0, hi = n;
    while (lo < hi) { int m = (lo + hi) >> 1; if (batch[m] < gid) lo = m + 1; else hi = m; }
    const int b0 = lo;
    hi = n;
    while (lo < hi) { int m = (lo + hi) >> 1; if (batch[m] < gid + 1) lo = m + 1; else hi = m; }
    const int b1 = lo;
    const int chunk = (b1 - b0 + PSPLIT - 1) / PSPLIT;
    const int r0 = b0 + part * chunk;
    const int r1 = min(r0 + chunk, b1);
    const int lane = threadIdx.x & 31;
    const int rg   = threadIdx.x >> 5;       // 8 rows in flight
    const __half2* hp = (const __half2*)h + lane;
    float2 acc = make_float2(0.f, 0.f);
    for (int i = r0 + rg; i < r1; i += 8) {
        float2 f = __half22float2(hp[(size_t)i * 32]);
        acc.x += f.x; acc.y += f.y;
    }
    __shared__ float2 red[8][32];
    red[rg][lane] = acc;
    __syncthreads();
    if (threadIdx.x < 32) {
        float2 s = make_float2(0.f, 0.f);
#pragma unroll
        for (int r = 0; r < 8; r++) { s.x += red[r][threadIdx.x].x; s.y += red[r][threadIdx.x].y; }
        atomicAdd(&pooled[gid * HID + 2 * threadIdx.x], s.x);
        atomicAdd(&pooled[gid * HID + 2 * threadIdx.x + 1], s.y);
    }

    // last block computes the value head once all pool partials have landed
    __threadfence();
    __shared__ int tk;
    if (threadIdx.x == 0) tk = atomicAdd(ticket, 1);
    __syncthreads();
    if (tk == g * PSPLIT - 1) {
        const int lane64 = threadIdx.x & 63;
        const int wv     = threadIdx.x >> 6;   // 0..3
        for (int gw = wv; gw < g; gw += 4) {
            int l2 = 0, h2 = n;
            while (l2 < h2) { int m = (l2 + h2) >> 1; if (batch[m] < gw) l2 = m + 1; else h2 = m; }
            int s0 = l2;
            h2 = n;
            while (l2 < h2) { int m = (l2 + h2) >> 1; if (batch[m] < gw + 1) l2 = m + 1; else h2 = m; }
            float cnt = fmaxf((float)(l2 - s0), 1.0f);
            float p = (pooled[gw * HID + lane64] / cnt) * Wc[lane64];
#pragma unroll
            for (int off = 32; off > 0; off >>= 1) p += __shfl_down(p, off);
            if (lane64 == 0) val[gw] = p + bc[0];
        }
    }
}

extern "C" void kernel_launch(void* const* d_in, const int* in_sizes, int n_in,
                              void* d_out, int out_size, void* d_ws, size_t ws_size,
                              hipStream_t stream) {
    const float* x     = (const float*)d_in[0];
    const int*   ei    = (const int*)d_in[1];
    const int*   batch = (const int*)d_in[2];
    const float* W1    = (const float*)d_in[3];
    const float* b1    = (const float*)d_in[4];
    const float* W2    = (const float*)d_in[5];
    const float* b2    = (const float*)d_in[6];
    const float* Wa    = (const float*)d_in[7];
    const float* ba    = (const float*)d_in[8];
    const float* Wc    = (const float*)d_in[9];
    const float* bc    = (const float*)d_in[10];

    const int n = in_sizes[0] / FEAT;   // 100000
    const int e = in_sizes[1] / 2;      // 1600000
    const int g = out_size - n;         // 64
    const int* src = ei;
    const int* dst = ei + e;

    const int nb = (n + BNODES - 1) >> BSH;   // buckets (782)
    const int L  = nb * PB;                    // offset table length

    // workspace layout. gather kernels must never write the buffer they
    // random-read: tS1=bufA -> tS2=bufB -> h2=bufA (tS1 dead by then).
    float*    ws     = (float*)d_ws;
    float*    dinv   = ws;                               // n
    float*    bufA   = dinv + n;                         // n*HID floats (tS1 fp16 / h2 fp16)
    float*    bufB   = bufA + (size_t)n * HID;           // n*HID floats (tS2 fp16)
    float*    pooled = bufB + (size_t)n * HID;           // g*HID
    int*      ticket = (int*)(pooled + (size_t)g * HID); // 1
    int*      table  = ticket + 1;                       // L
    int*      aux    = table + L;                        // 1024
    int*      rowptr = aux + 1024;                       // n+1
    int*      col    = rowptr + n + 1;                   // e
    unsigned* packed = (unsigned*)bufA;                  // e (aliased, transient)
    __half*   tS1    = (__half*)bufA;                    // layer-1 transformed
    __half*   tS2    = (__half*)bufB;                    // layer-2 transformed (gather1t2 out)
    __half*   h2     = (__half*)bufA;                    // layer-2 h (gather2 out)

    const int B = 256;
    const int gridT  = (n + 63) / 64;
    const int gridG  = (int)(((size_t)n * 32 + B - 1) / B);  // 32-lane group per node
    const int gridF  = (n + 15) / 16;                         // fused gather1+t2 (512 thr)
    const int nb1    = (L + 1023) / 1024;

    // CSR build (proven 2-level bucket sort; high occupancy)
    part_hist_k<<<PB, B, 0, stream>>>(dst, table, pooled, ticket, e, nb, g * HID);
    scan1_k<<<nb1, 1024, 0, stream>>>(table, aux, L);
    scan2_k<<<1, 1024, 0, stream>>>(aux, nb1);
    part_scatter_k<<<PB, B, 0, stream>>>(src, dst, table, aux, packed, e, nb);
    bucket_sort_k<<<nb, B, 0, stream>>>(packed, table, aux, col, rowptr, dinv, n, e, nb);

    // layer 1: dense transform, then gather fused with MFMA h@W2*dinv -> tS2 (bufB)
    gemm_tile_k<<<gridT, B, 0, stream>>>(x, W1, dinv, tS1, n);
    gather1t2_k<<<gridF, 512, 0, stream>>>(tS1, rowptr, col, dinv, b1, W2, tS2, n);

    // layer 2 gather (logits fused; h2 -> bufA)
    gather2_k<<<gridG, B, 0, stream>>>(tS2, rowptr, col, dinv, b2, h2,
                                       Wa, ba, (float*)d_out, n);

    // fused mean-pool + value head
    poolvalue_k<<<g * PSPLIT, B, 0, stream>>>(h2, batch, pooled, ticket, Wc, bc,
                                              (float*)d_out + n, n, g);
}

// Round 14
// 293.846 us; speedup vs baseline: 1.5787x; 1.5787x over previous
//
#include <hip/hip_runtime.h>
#include <hip/hip_fp16.h>
#include <math.h>

#define FEAT 128
#define HID  64
#define BSH  7                 // 128 dst-nodes per bucket
#define BNODES (1 << BSH)
#define PB   256               // partition blocks (256: full-chip parallelism)
#define SRCM ((1u << 25) - 1)  // src in low 25 bits, dst_local in high 7
#define PSPLIT 16              // pool splits per group

typedef _Float16 f16_t;
typedef f16_t half8 __attribute__((ext_vector_type(8)));
typedef float  f32x4 __attribute__((ext_vector_type(4)));

// ---------------- stage 1: edge partition by dst-bucket ----------------
// block 0 additionally zeroes pooled[] (replaces a hipMemsetAsync dispatch;
// stream order guarantees visibility before pool2_k).

__global__ void part_hist_k(const int* __restrict__ dst, int* __restrict__ table,
                            float* __restrict__ pooled, int e, int nb, int gh) {
    if (blockIdx.x == 0) {
        for (int i = threadIdx.x; i < gh; i += 256) pooled[i] = 0.0f;
    }
    __shared__ int lcnt[1024];
    for (int i = threadIdx.x; i < nb; i += 256) lcnt[i] = 0;
    __syncthreads();
    int eb = (e + PB - 1) / PB;
    int lo = blockIdx.x * eb, hi = min(lo + eb, e);
    for (int i = lo + threadIdx.x; i < hi; i += 256)
        atomicAdd(&lcnt[dst[i] >> BSH], 1);
    __syncthreads();
    for (int k = threadIdx.x; k < nb; k += 256)
        table[k * PB + blockIdx.x] = lcnt[k];
}

__global__ void scan1_k(int* __restrict__ data, int* __restrict__ aux, int L) {
    __shared__ int s[1024];
    int gid = blockIdx.x * 1024 + threadIdx.x;
    int v = (gid < L) ? data[gid] : 0;
    s[threadIdx.x] = v;
    __syncthreads();
    for (int off = 1; off < 1024; off <<= 1) {
        int t = (threadIdx.x >= off) ? s[threadIdx.x - off] : 0;
        __syncthreads();
        s[threadIdx.x] += t;
        __syncthreads();
    }
    if (gid < L) data[gid] = s[threadIdx.x] - v;            // exclusive in block
    if (threadIdx.x == 1023) aux[blockIdx.x] = s[1023];     // block total
}

__global__ void scan2_k(int* aux, int naux) {
    __shared__ int s[1024];
    int v = (threadIdx.x < naux) ? aux[threadIdx.x] : 0;
    s[threadIdx.x] = v;
    __syncthreads();
    for (int off = 1; off < 1024; off <<= 1) {
        int t = (threadIdx.x >= off) ? s[threadIdx.x - off] : 0;
        __syncthreads();
        s[threadIdx.x] += t;
        __syncthreads();
    }
    if (threadIdx.x < naux) aux[threadIdx.x] = s[threadIdx.x] - v;
}

__global__ void part_scatter_k(const int* __restrict__ src, const int* __restrict__ dst,
                               const int* __restrict__ table, const int* __restrict__ aux,
                               unsigned* __restrict__ packed, int e, int nb) {
    __shared__ int loff[1024];
    for (int k = threadIdx.x; k < nb; k += 256) {
        int idx = k * PB + blockIdx.x;
        loff[k] = table[idx] + aux[idx >> 10];
    }
    __syncthreads();
    int eb = (e + PB - 1) / PB;
    int lo = blockIdx.x * eb, hi = min(lo + eb, e);
    for (int i = lo + threadIdx.x; i < hi; i += 256) {
        int d = dst[i];
        int p = atomicAdd(&loff[d >> BSH], 1);
        packed[p] = ((unsigned)(d & (BNODES - 1)) << 25) | (unsigned)src[i];
    }
}

// ---------------- stage 2: per-bucket counting sort -> per-node CSR + dinv ----

__global__ void bucket_sort_k(const unsigned* __restrict__ packed,
                              const int* __restrict__ table, const int* __restrict__ aux,
                              int* __restrict__ col, int* __restrict__ rowptr,
                              float* __restrict__ dinv, int n, int e, int nb) {
    __shared__ int cnt[BNODES];
    __shared__ int s[BNODES];
    __shared__ int cur[BNODES];
    const int k = blockIdx.x;
    const int t = threadIdx.x;
    if (t < BNODES) cnt[t] = 0;
    __syncthreads();
    int i0 = k * PB;
    int i1 = (k + 1) * PB;
    const int bs = table[i0] + aux[i0 >> 10];
    const int be = (k + 1 < nb) ? (table[i1] + aux[i1 >> 10]) : e;
    for (int i = bs + t; i < be; i += 256)
        atomicAdd(&cnt[packed[i] >> 25], 1);
    __syncthreads();
    if (t < BNODES) s[t] = cnt[t];
    __syncthreads();
    for (int off = 1; off < BNODES; off <<= 1) {
        int v = (t < BNODES && t >= off) ? s[t - off] : 0;
        __syncthreads();
        if (t < BNODES) s[t] += v;
        __syncthreads();
    }
    if (t < BNODES) {
        int base = bs + s[t] - cnt[t];
        cur[t] = base;
        int node = (k << BSH) + t;
        if (node < n) {
            rowptr[node] = base;
            dinv[node] = 1.0f / sqrtf(1.0f + (float)cnt[t]);
            if (node == n - 1) rowptr[n] = base + cnt[t];
        }
    }
    __syncthreads();
    for (int i = bs + t; i < be; i += 256) {
        unsigned u = packed[i];
        int p = atomicAdd(&cur[u >> 25], 1);
        col[p] = (int)(u & SRCM);
    }
}

// ---------------- dense transform: out[n,64] = fp16((X[n,128] @ W1) * dinv[row]) ----

__global__ __launch_bounds__(256, 3)
void gemm_tile_k(const float* __restrict__ X, const float* __restrict__ W,
                 const float* __restrict__ dinv, __half* __restrict__ out, int n) {
    constexpr int K = FEAT;
    __shared__ float sX[64][K + 4];
    __shared__ float sW[64][64];       // one 64-row slab of W
    const int row0 = blockIdx.x * 64;
    const int t  = threadIdx.x;
    const int tx = t & 15;
    const int ty = t >> 4;

    const float* xb = X + (size_t)row0 * K;
#pragma unroll
    for (int it = 0; it < K / 16; ++it) {
        int fl = it * 1024 + t * 4;
        int r  = fl >> 7;
        int k  = fl & (K - 1);
        float4 v = make_float4(0.f, 0.f, 0.f, 0.f);
        if (row0 + r < n) v = *(const float4*)(xb + fl);
        *(float4*)&sX[r][k] = v;
    }

    float acc[4][4] = {};
#pragma unroll
    for (int ph = 0; ph < K / 64; ++ph) {
        __syncthreads();
#pragma unroll
        for (int it = 0; it < 4; ++it) {
            int fl = it * 1024 + t * 4;
            *(float4*)&sW[fl >> 6][fl & 63] = *(const float4*)(W + ph * 64 * HID + fl);
        }
        __syncthreads();

#pragma unroll 8
        for (int k = 0; k < 64; k += 4) {
            float4 a[4], b[4];
#pragma unroll
            for (int i = 0; i < 4; i++) a[i] = *(float4*)&sX[ty * 4 + i][ph * 64 + k];
#pragma unroll
            for (int j = 0; j < 4; j++) b[j] = *(float4*)&sW[k + j][tx * 4];
#pragma unroll
            for (int i = 0; i < 4; i++) {
                acc[i][0] = fmaf(a[i].x, b[0].x, acc[i][0]);
                acc[i][1] = fmaf(a[i].x, b[0].y, acc[i][1]);
                acc[i][2] = fmaf(a[i].x, b[0].z, acc[i][2]);
                acc[i][3] = fmaf(a[i].x, b[0].w, acc[i][3]);
                acc[i][0] = fmaf(a[i].y, b[1].x, acc[i][0]);
                acc[i][1] = fmaf(a[i].y, b[1].y, acc[i][1]);
                acc[i][2] = fmaf(a[i].y, b[1].z, acc[i][2]);
                acc[i][3] = fmaf(a[i].y, b[1].w, acc[i][3]);
                acc[i][0] = fmaf(a[i].z, b[2].x, acc[i][0]);
                acc[i][1] = fmaf(a[i].z, b[2].y, acc[i][1]);
                acc[i][2] = fmaf(a[i].z, b[2].z, acc[i][2]);
                acc[i][3] = fmaf(a[i].z, b[2].w, acc[i][3]);
                acc[i][0] = fmaf(a[i].w, b[3].x, acc[i][0]);
                acc[i][1] = fmaf(a[i].w, b[3].y, acc[i][1]);
                acc[i][2] = fmaf(a[i].w, b[3].z, acc[i][2]);
                acc[i][3] = fmaf(a[i].w, b[3].w, acc[i][3]);
            }
        }
    }

#pragma unroll
    for (int i = 0; i < 4; i++) {
        int gr = row0 + ty * 4 + i;
        if (gr < n) {
            float sc = dinv[gr];
            union { __half2 h[2]; unsigned long long u; } pk;
            pk.h[0] = __floats2half2_rn(acc[i][0] * sc, acc[i][1] * sc);
            pk.h[1] = __floats2half2_rn(acc[i][2] * sc, acc[i][3] * sc);
            *(unsigned long long*)(out + (size_t)gr * HID + tx * 4) = pk.u;
        }
    }
}

// ---------------- layer-1 gather + MFMA t2 fused (512 thr = 16 nodes = 1 strip) ----
// out (tS2) must NOT alias the gather input tS (inter-block race — round 11).

__global__ __launch_bounds__(512)
void gather1t2_k(const __half* __restrict__ tS, const int* __restrict__ rowptr,
                 const int* __restrict__ col, const float* __restrict__ dinv,
                 const float* __restrict__ b, const float* __restrict__ W2,
                 __half* __restrict__ out, int n) {
    __shared__ __half sh[16][72];      // h rows (stride 72: 2-way banks, 16B-aligned frags)
    const int tid  = threadIdx.x;
    const int nl   = tid >> 5;         // node-local 0..15
    const int lane = tid & 31;
    const int r0   = blockIdx.x * 16;
    const int node = r0 + nl;

    float h0 = 0.f, h1 = 0.f;
    if (node < n) {
        int beg = rowptr[node], end = rowptr[node + 1];
        const __half2* tl = (const __half2*)tS + lane;   // row stride = 32 half2
        float2 acc = __half22float2(tl[node * 32]);      // self-loop term
        int e = beg;
        for (; e + 16 <= end; e += 16) {
            int s[16];
            __half2 v[16];
#pragma unroll
            for (int j = 0; j < 16; j++) s[j] = col[e + j];
#pragma unroll
            for (int j = 0; j < 16; j++) v[j] = tl[s[j] * 32];
            float2 t0 = make_float2(0.f, 0.f), t1 = make_float2(0.f, 0.f);
#pragma unroll
            for (int j = 0; j < 8; j++) {
                float2 f = __half22float2(v[j]);
                t0.x += f.x; t0.y += f.y;
            }
#pragma unroll
            for (int j = 8; j < 16; j++) {
                float2 f = __half22float2(v[j]);
                t1.x += f.x; t1.y += f.y;
            }
            acc.x += t0.x + t1.x;
            acc.y += t0.y + t1.y;
        }
        for (; e + 4 <= end; e += 4) {
            __half2 v0 = tl[col[e] * 32];
            __half2 v1 = tl[col[e + 1] * 32];
            __half2 v2 = tl[col[e + 2] * 32];
            __half2 v3 = tl[col[e + 3] * 32];
            float2 f0 = __half22float2(v0), f1 = __half22float2(v1);
            float2 f2 = __half22float2(v2), f3 = __half22float2(v3);
            acc.x += (f0.x + f1.x) + (f2.x + f3.x);
            acc.y += (f0.y + f1.y) + (f2.y + f3.y);
        }
        for (; e < end; ++e) {
            float2 f = __half22float2(tl[col[e] * 32]);
            acc.x += f.x; acc.y += f.y;
        }
        float d = dinv[node];
        float2 bb = *(const float2*)(b + 2 * lane);
        h0 = fmaxf(fmaf(d, acc.x, bb.x), 0.0f);
        h1 = fmaxf(fmaf(d, acc.y, bb.y), 0.0f);
    }
    *(__half2*)&sh[nl][2 * lane] = __floats2half2_rn(h0, h1);
    __syncthreads();

    const int w = tid >> 6;            // wave 0..7
    if (w < 4) {
        const int l    = tid & 63;
        const int colc = l & 15;
        const int kb   = l >> 4;       // 0..3
        const int t    = w;            // 16-col tile
        // B-frags (W2 fp32 -> fp16; L2-resident)
        half8 b0, b1;
#pragma unroll
        for (int j = 0; j < 8; ++j)
            b0[j] = (f16_t)W2[(kb * 8 + j) * HID + t * 16 + colc];
#pragma unroll
        for (int j = 0; j < 8; ++j)
            b1[j] = (f16_t)W2[(32 + kb * 8 + j) * HID + t * 16 + colc];
        // A-frags from LDS: row = colc, k = kb*8 (+32)
        half8 a0 = *(const half8*)&sh[colc][kb * 8];
        half8 a1 = *(const half8*)&sh[colc][32 + kb * 8];
        f32x4 acc = {};
        acc = __builtin_amdgcn_mfma_f32_16x16x32_f16(a0, b0, acc, 0, 0, 0);
        acc = __builtin_amdgcn_mfma_f32_16x16x32_f16(a1, b1, acc, 0, 0, 0);
        const int rbase = r0 + kb * 4;
#pragma unroll
        for (int r = 0; r < 4; ++r) {
            int gr = rbase + r;
            if (gr < n) {
                float dv = dinv[gr];
                out[(size_t)gr * HID + t * 16 + colc] = __float2half(acc[r] * dv);
            }
        }
    }
}

// ---------------- layer-2 gather (logits fused; h written fp16 for pool) ----

__global__ void gather2_k(const __half* __restrict__ tS, const int* __restrict__ rowptr,
                          const int* __restrict__ col, const float* __restrict__ dinv,
                          const float* __restrict__ b, __half* __restrict__ out,
                          const float* __restrict__ Wa, const float* __restrict__ ba,
                          float* __restrict__ logits, int n) {
    int node = (int)((blockIdx.x * (size_t)blockDim.x + threadIdx.x) >> 5);
    int lane = threadIdx.x & 31;
    if (node >= n) return;
    int beg = rowptr[node], end = rowptr[node + 1];
    const __half2* tl = (const __half2*)tS + lane;
    float2 acc = __half22float2(tl[node * 32]);
    int e = beg;
    for (; e + 16 <= end; e += 16) {
        int s[16];
        __half2 v[16];
#pragma unroll
        for (int j = 0; j < 16; j++) s[j] = col[e + j];
#pragma unroll
        for (int j = 0; j < 16; j++) v[j] = tl[s[j] * 32];
        float2 t0 = make_float2(0.f, 0.f), t1 = make_float2(0.f, 0.f);
#pragma unroll
        for (int j = 0; j < 8; j++) {
            float2 f = __half22float2(v[j]);
            t0.x += f.x; t0.y += f.y;
        }
#pragma unroll
        for (int j = 8; j < 16; j++) {
            float2 f = __half22float2(v[j]);
            t1.x += f.x; t1.y += f.y;
        }
        acc.x += t0.x + t1.x;
        acc.y += t0.y + t1.y;
    }
    for (; e + 4 <= end; e += 4) {
        __half2 v0 = tl[col[e] * 32];
        __half2 v1 = tl[col[e + 1] * 32];
        __half2 v2 = tl[col[e + 2] * 32];
        __half2 v3 = tl[col[e + 3] * 32];
        float2 f0 = __half22float2(v0), f1 = __half22float2(v1);
        float2 f2 = __half22float2(v2), f3 = __half22float2(v3);
        acc.x += (f0.x + f1.x) + (f2.x + f3.x);
        acc.y += (f0.y + f1.y) + (f2.y + f3.y);
    }
    for (; e < end; ++e) {
        float2 f = __half22float2(tl[col[e] * 32]);
        acc.x += f.x; acc.y += f.y;
    }
    float d = dinv[node];
    float2 bb = *(const float2*)(b + 2 * lane);
    float h0 = fmaxf(fmaf(d, acc.x, bb.x), 0.0f);
    float h1 = fmaxf(fmaf(d, acc.y, bb.y), 0.0f);
    ((__half2*)out)[node * 32 + lane] = __floats2half2_rn(h0, h1);
    float2 wa = *(const float2*)(Wa + 2 * lane);
    float p = h0 * wa.x + h1 * wa.y;
#pragma unroll
    for (int off = 16; off > 0; off >>= 1) p += __shfl_down(p, off, 32);
    if (lane == 0) logits[node] = p + ba[0];
}

// ---------------- parallel mean-pool: 64 groups x 16 splits, branch-free ----

__global__ void pool2_k(const __half* __restrict__ h, const int* __restrict__ batch,
                        float* __restrict__ pooled, int n) {
    const int gid  = blockIdx.x / PSPLIT;
    const int part = blockIdx.x % PSPLIT;
    int lo = 0, hi = n;
    while (lo < hi) { int m = (lo + hi) >> 1; if (batch[m] < gid) lo = m + 1; else hi = m; }
    const int b0 = lo;
    hi = n;
    while (lo < hi) { int m = (lo + hi) >> 1; if (batch[m] < gid + 1) lo = m + 1; else hi = m; }
    const int b1 = lo;
    const int chunk = (b1 - b0 + PSPLIT - 1) / PSPLIT;
    const int r0 = b0 + part * chunk;
    const int r1 = min(r0 + chunk, b1);
    const int lane = threadIdx.x & 31;
    const int rg   = threadIdx.x >> 5;       // 8 rows in flight
    const __half2* hp = (const __half2*)h + lane;
    float2 acc = make_float2(0.f, 0.f);
    for (int i = r0 + rg; i < r1; i += 8) {
        float2 f = __half22float2(hp[(size_t)i * 32]);
        acc.x += f.x; acc.y += f.y;
    }
    __shared__ float2 red[8][32];
    red[rg][lane] = acc;
    __syncthreads();
    if (threadIdx.x < 32) {
        float2 s = make_float2(0.f, 0.f);
#pragma unroll
        for (int r = 0; r < 8; r++) { s.x += red[r][threadIdx.x].x; s.y += red[r][threadIdx.x].y; }
        atomicAdd(&pooled[gid * HID + 2 * threadIdx.x], s.x);
        atomicAdd(&pooled[gid * HID + 2 * threadIdx.x + 1], s.y);
    }
}

// ---------------- value head (counts via binary search; 64 parallel waves) ----

__global__ void value_k(const float* __restrict__ pooled, const int* __restrict__ batch,
                        const float* __restrict__ Wc, const float* __restrict__ bc,
                        float* __restrict__ val, int n, int g) {
    int gw   = (int)((blockIdx.x * (size_t)blockDim.x + threadIdx.x) >> 6);
    int lane = threadIdx.x & 63;
    if (gw >= g) return;
    int lo = 0, hi = n;
    while (lo < hi) { int m = (lo + hi) >> 1; if (batch[m] < gw) lo = m + 1; else hi = m; }
    int b0 = lo;
    lo = 0; hi = n;
    while (lo < hi) { int m = (lo + hi) >> 1; if (batch[m] < gw + 1) lo = m + 1; else hi = m; }
    float cnt = fmaxf((float)(lo - b0), 1.0f);
    float p = (pooled[gw * HID + lane] / cnt) * Wc[lane];
#pragma unroll
    for (int off = 32; off > 0; off >>= 1) p += __shfl_down(p, off);
    if (lane == 0) val[gw] = p + bc[0];
}

extern "C" void kernel_launch(void* const* d_in, const int* in_sizes, int n_in,
                              void* d_out, int out_size, void* d_ws, size_t ws_size,
                              hipStream_t stream) {
    const float* x     = (const float*)d_in[0];
    const int*   ei    = (const int*)d_in[1];
    const int*   batch = (const int*)d_in[2];
    const float* W1    = (const float*)d_in[3];
    const float* b1    = (const float*)d_in[4];
    const float* W2    = (const float*)d_in[5];
    const float* b2    = (const float*)d_in[6];
    const float* Wa    = (const float*)d_in[7];
    const float* ba    = (const float*)d_in[8];
    const float* Wc    = (const float*)d_in[9];
    const float* bc    = (const float*)d_in[10];

    const int n = in_sizes[0] / FEAT;   // 100000
    const int e = in_sizes[1] / 2;      // 1600000
    const int g = out_size - n;         // 64
    const int* src = ei;
    const int* dst = ei + e;

    const int nb = (n + BNODES - 1) >> BSH;   // buckets (782)
    const int L  = nb * PB;                    // offset table length

    // workspace layout. gather kernels must never write the buffer they
    // random-read: tS1=bufA -> tS2=bufB -> h2=bufA (tS1 dead by then).
    float*    ws     = (float*)d_ws;
    float*    dinv   = ws;                               // n
    float*    bufA   = dinv + n;                         // n*HID floats (tS1 fp16 / h2 fp16)
    float*    bufB   = bufA + (size_t)n * HID;           // n*HID floats (tS2 fp16)
    float*    pooled = bufB + (size_t)n * HID;           // g*HID
    int*      table  = (int*)(pooled + (size_t)g * HID); // L
    int*      aux    = table + L;                        // 1024
    int*      rowptr = aux + 1024;                       // n+1
    int*      col    = rowptr + n + 1;                   // e
    unsigned* packed = (unsigned*)bufA;                  // e (aliased, transient)
    __half*   tS1    = (__half*)bufA;                    // layer-1 transformed
    __half*   tS2    = (__half*)bufB;                    // layer-2 transformed (gather1t2 out)
    __half*   h2     = (__half*)bufA;                    // layer-2 h (gather2 out)

    const int B = 256;
    const int gridT  = (n + 63) / 64;
    const int gridG  = (int)(((size_t)n * 32 + B - 1) / B);  // 32-lane group per node
    const int gridF  = (n + 15) / 16;                         // fused gather1+t2 (512 thr)
    const int nb1    = (L + 1023) / 1024;

    // CSR build (proven 2-level bucket sort; high occupancy)
    part_hist_k<<<PB, B, 0, stream>>>(dst, table, pooled, e, nb, g * HID);
    scan1_k<<<nb1, 1024, 0, stream>>>(table, aux, L);
    scan2_k<<<1, 1024, 0, stream>>>(aux, nb1);
    part_scatter_k<<<PB, B, 0, stream>>>(src, dst, table, aux, packed, e, nb);
    bucket_sort_k<<<nb, B, 0, stream>>>(packed, table, aux, col, rowptr, dinv, n, e, nb);

    // layer 1: dense transform, then gather fused with MFMA h@W2*dinv -> tS2 (bufB)
    gemm_tile_k<<<gridT, B, 0, stream>>>(x, W1, dinv, tS1, n);
    gather1t2_k<<<gridF, 512, 0, stream>>>(tS1, rowptr, col, dinv, b1, W2, tS2, n);

    // layer 2 gather (logits fused; h2 -> bufA)
    gather2_k<<<gridG, B, 0, stream>>>(tS2, rowptr, col, dinv, b2, h2,
                                       Wa, ba, (float*)d_out, n);

    // heads (parallel: 1024 pool blocks, then 64 parallel value waves)
    pool2_k<<<g * PSPLIT, B, 0, stream>>>(h2, batch, pooled, n);
    value_k<<<(g * 64 + B - 1) / B, B, 0, stream>>>(pooled, batch, Wc, bc,
                                                    (float*)d_out + n, n, g);
}